// Round 14
// baseline (255.518 us; speedup 1.0000x reference)
//
#include <hip/hip_runtime.h>
#include <stdint.h>
#include <math.h>

// ---------- types ----------
typedef float f32x4 __attribute__((ext_vector_type(4)));
typedef __bf16 bf16x8 __attribute__((ext_vector_type(8)));

#define DEVI __device__ __forceinline__

#if __has_builtin(__builtin_amdgcn_exp2f)
#define EXP2(x) __builtin_amdgcn_exp2f(x)
#else
#define EXP2(x) exp2f(x)
#endif

#define LOG2E 1.44269504f

DEVI unsigned short f2bf(float f) {
  union { float f; unsigned int u; } c; c.f = f;
  unsigned int u = c.u;
  return (unsigned short)((u + 0x7FFFu + ((u >> 16) & 1u)) >> 16);  // RTN-even
}

// cheap round-half-up (P values only; numerator & denominator share values)
DEVI unsigned short f2bf_fast(float f) {
  union { float f; unsigned int u; } c; c.f = f;
  return (unsigned short)((c.u + 0x8000u) >> 16);
}

// async global->LDS, 16B per lane. LDS dest must be wave-uniform base + lane*16.
DEVI void gll16(const void* g, void* l) {
  __builtin_amdgcn_global_load_lds(
      (const __attribute__((address_space(1))) void*)g,
      (__attribute__((address_space(3))) void*)l,
      16, 0, 0);
}

// ---------- fp32 -> bf16: all four weight matrices in ONE launch ----------
__global__ __launch_bounds__(256) void cvt_weights(
    const float* __restrict__ Wq, const float* __restrict__ Wk,
    const float* __restrict__ Wv, const float* __restrict__ Wo,
    unsigned short* __restrict__ WB, unsigned short* __restrict__ WoB) {
  int i = blockIdx.x * 256 + threadIdx.x;  // 0 .. 4*262144-1 (float4 units)
  int seg = i >> 18;                       // 262144 float4 per matrix
  int j = i & 262143;
  const float* src = (seg == 0) ? Wq : (seg == 1) ? Wk : (seg == 2) ? Wv : Wo;
  unsigned short* dst = (seg < 3) ? WB + (size_t)seg * 1048576 : WoB;
  float4 v = ((const float4*)src)[j];
  ushort4 ov;
  ov.x = f2bf(v.x); ov.y = f2bf(v.y); ov.z = f2bf(v.z); ov.w = f2bf(v.w);
  ((ushort4*)dst)[j] = ov;
}

// ---------- fp32 R x C  ->  bf16 C x R (transpose) ----------
__global__ __launch_bounds__(256) void transpose_f32_bf16(
    const float* __restrict__ in, unsigned short* __restrict__ out, int R, int C) {
  __shared__ float tile[32][33];
  int bc = blockIdx.x * 32, br = blockIdx.y * 32;
  int tx = threadIdx.x & 31, ty = threadIdx.x >> 5;  // ty 0..7
#pragma unroll
  for (int i = 0; i < 32; i += 8)
    tile[ty + i][tx] = in[(size_t)(br + ty + i) * C + bc + tx];
  __syncthreads();
#pragma unroll
  for (int i = 0; i < 32; i += 8)
    out[(size_t)(bc + ty + i) * R + br + tx] = f2bf(tile[tx][ty + i]);
}

// ---------- V transpose: QKV[t][2048+h*64+d] -> Vt[bh][d][s] (bf16) ----------
__global__ __launch_bounds__(256) void vtrans(
    const unsigned short* __restrict__ QKV, unsigned short* __restrict__ Vt) {
  int stile = blockIdx.x;  // 0..31 (64 tokens each)
  int bh = blockIdx.y;     // 0..31
  int b = bh >> 4, h = bh & 15;
  __shared__ unsigned short tile[64][68];
  const unsigned short* src =
      QKV + ((size_t)(b * 2048 + stile * 64)) * 3072 + 2048 + h * 64;
  int t = threadIdx.x;
#pragma unroll
  for (int i = 0; i < 16; i++) {
    int e = i * 256 + t; int s = e >> 6, d = e & 63;
    tile[s][d] = src[(size_t)s * 3072 + d];
  }
  __syncthreads();
  unsigned short* dst = Vt + (size_t)bh * 64 * 2048 + stile * 64;
#pragma unroll
  for (int i = 0; i < 16; i++) {
    int e = i * 256 + t; int d = e >> 6, s = e & 63;
    dst[(size_t)d * 2048 + s] = tile[s][d];
  }
}

// ---------- LayerNorm fp32 -> bf16 ----------
__global__ __launch_bounds__(256) void layernorm_bf16(
    const float* __restrict__ x, const float* __restrict__ g,
    const float* __restrict__ be, unsigned short* __restrict__ out) {
  const int row = blockIdx.x;
  const int t = threadIdx.x;
  const float4 v = ((const float4*)(x + (size_t)row * 1024))[t];
  float s = v.x + v.y + v.z + v.w;
  float s2 = v.x * v.x + v.y * v.y + v.z * v.z + v.w * v.w;
#pragma unroll
  for (int d = 32; d > 0; d >>= 1) {
    s += __shfl_down(s, d);
    s2 += __shfl_down(s2, d);
  }
  __shared__ float ps[4], ps2[4], st[2];
  const int lane = t & 63, wave = t >> 6;
  if (lane == 0) { ps[wave] = s; ps2[wave] = s2; }
  __syncthreads();
  if (t == 0) {
    float S = ps[0] + ps[1] + ps[2] + ps[3];
    float S2 = ps2[0] + ps2[1] + ps2[2] + ps2[3];
    float mu = S * (1.0f / 1024.0f);
    float var = S2 * (1.0f / 1024.0f) - mu * mu;
    st[0] = mu; st[1] = rsqrtf(var + 1e-5f);
  }
  __syncthreads();
  float mu = st[0], inv = st[1];
  float4 gv = ((const float4*)g)[t];
  float4 bv = ((const float4*)be)[t];
  ushort4 ov;
  ov.x = f2bf((v.x - mu) * inv * gv.x + bv.x);
  ov.y = f2bf((v.y - mu) * inv * gv.y + bv.y);
  ov.z = f2bf((v.z - mu) * inv * gv.z + bv.z);
  ov.w = f2bf((v.w - mu) * inv * gv.w + bv.w);
  ((ushort4*)(out + (size_t)row * 1024))[t] = ov;
}

// exp2-based tanh-gelu: x / (1 + 2^-(c3*x + c4*x^3))
DEVI float gelu_f(float x) {
  float a = x * (2.3022082f + 0.1029432f * x * x);
  return x / (1.0f + EXP2(-a));
}

// ---------- GEMM: C[M,N] = A[M,K] * B[N,K]^T  (bf16 in, f32 acc) ----------
// Round-7 verified config: 2-phase double-buffered LDS + row-pair-packed
// XOR-swizzled LDS (0 conflicts measured). 128x128 for QKV/FFN1; 64x128
// for the N=1024 GEMMs (2 blocks/CU).
// EPI 0: outB = bf16(C)
// EPI 1: outF = res + C
// EPI 2: outB = bf16(gelu(C + bias))
// EPI 3: outF = res + C + bias
template <int EPI, int TM, int TN>
__global__ __launch_bounds__(256, 4) void gemm_bt(
    const unsigned short* __restrict__ A, const unsigned short* __restrict__ B,
    int M, int N, int K, float* __restrict__ outF, unsigned short* __restrict__ outB,
    const float* __restrict__ res, const float* __restrict__ bias) {
  __shared__ __align__(16) unsigned short As[2][TM * 32];
  __shared__ __align__(16) unsigned short Bs[2][TN * 32];
  constexpr int MF = TM / 32;  // m fragments per wave
  constexpr int NF = TN / 32;  // n fragments per wave
  const int t = threadIdx.x;
  const int lane = t & 63, wave = t >> 6;
  const int wr = wave >> 1, wc = wave & 1;
  const int l15 = lane & 15, lg = lane >> 4;
  // stage-side swizzle: lane t writes LDS row r=(t>>3), phys slot s=(t&7);
  // that slot's logical content is slot sl = s ^ (r&7) of row-pair r.
  const int sl = (t & 7) ^ ((t >> 3) & 7);
  const int srow2 = ((t >> 3) << 1) + (sl >> 2);  // global row within 64-row chunk
  const int scol2 = (sl & 3) * 8;                 // elem offset within row
  // XCD-aware bijective swizzle (nwg % 8 == 0 for all our grids)
  const int gx = gridDim.x;
  const int nwg = gx * gridDim.y;
  const int orig = blockIdx.y * gx + blockIdx.x;
  const int swz = (orig & 7) * (nwg >> 3) + (orig >> 3);
  const int bx = swz % gx, by = swz / gx;
  const size_t aBase = (size_t)by * TM * K;
  const size_t bBase = (size_t)bx * TN * K;
  f32x4 acc[MF][NF] = {};

  auto stage = [&](int buf, int kt) {
#pragma unroll
    for (int i = 0; i < TM / 64; i++)
      gll16(A + aBase + (size_t)(srow2 + i * 64) * K + kt + scol2,
            (char*)&As[buf][0] + i * 4096 + t * 16);
#pragma unroll
    for (int i = 0; i < TN / 64; i++)
      gll16(B + bBase + (size_t)(srow2 + i * 64) * K + kt + scol2,
            (char*)&Bs[buf][0] + i * 4096 + t * 16);
  };

  stage(0, 0);
  __syncthreads();
  const int nk = K >> 5;
  for (int ki = 0; ki < nk; ki++) {
    const int cur = ki & 1;
    if (ki + 1 < nk) stage(cur ^ 1, (ki + 1) << 5);  // overlap with compute
    bf16x8 af[MF], bfv[NF];
#pragma unroll
    for (int m = 0; m < MF; m++) {
      const int R = wr * (TM / 2) + m * 16 + l15;
      const int r = R >> 1;
      const int ps = (((R & 1) << 2) | lg) ^ (r & 7);
      af[m] = *(const bf16x8*)&As[cur][r * 64 + ps * 8];
    }
#pragma unroll
    for (int n = 0; n < NF; n++) {
      const int R = wc * (TN / 2) + n * 16 + l15;
      const int r = R >> 1;
      const int ps = (((R & 1) << 2) | lg) ^ (r & 7);
      bfv[n] = *(const bf16x8*)&Bs[cur][r * 64 + ps * 8];
    }
#pragma unroll
    for (int m = 0; m < MF; m++)
#pragma unroll
      for (int n = 0; n < NF; n++)
        acc[m][n] = __builtin_amdgcn_mfma_f32_16x16x32_bf16(af[m], bfv[n], acc[m][n], 0, 0, 0);
    __syncthreads();  // drains prefetch (vmcnt 0) + protects cur for next overwrite
  }
  const int rowB = by * TM + wr * (TM / 2);
  const int colB = bx * TN + wc * (TN / 2);
#pragma unroll
  for (int m = 0; m < MF; m++) {
#pragma unroll
    for (int n = 0; n < NF; n++) {
#pragma unroll
      for (int r = 0; r < 4; r++) {
        int gm = rowB + m * 16 + lg * 4 + r;
        int gn = colB + n * 16 + l15;
        float c = acc[m][n][r];
        size_t idx = (size_t)gm * N + gn;
        if (EPI == 0) {
          outB[idx] = f2bf(c);
        } else if (EPI == 1) {
          outF[idx] = res[idx] + c;
        } else if (EPI == 2) {
          outB[idx] = f2bf(gelu_f(c + bias[gn]));
        } else {
          outF[idx] = res[idx] + c + bias[gn];
        }
      }
    }
  }
}

// ---------- flash attention, static-max softmax, QBLK=128 -----------------
// Round 14: QK^T computed with SWAPPED operands (mfma(K,Q) -> S^T), so each
// lane holds 4 CONSECUTIVE keys (n*16+lg*4+r) for one q-row (q=..+l15).
// P-store becomes one 8B ds_write per (fi,n): 32 ds_write_b16 -> 8
// ds_write_b64 per K-tile per thread. The XOR swizzle flips only bit4
// (16B slot), preserving each 8B half -> physical layout identical to what
// the (unchanged) PV-side reads expect. P rows remain wave-private.
// Everything else identical to the verified r13 kernel.
__global__ __launch_bounds__(256) void attn_flash(
    const unsigned short* __restrict__ QKV, const unsigned short* __restrict__ Vt,
    unsigned short* __restrict__ attnO) {
  __shared__ __align__(16) unsigned short Ks[2][64 * 64];
  __shared__ __align__(16) unsigned short Vs[2][64 * 64];
  __shared__ __align__(16) unsigned short Ps[128 * 64];
  const int t = threadIdx.x;
  const int lane = t & 63, wave = t >> 6;
  const int l15 = lane & 15, lg = lane >> 4;
  const int bid = blockIdx.x;
  const int swzb = (bid & 7) * 64 + (bid >> 3);
  const int qt = swzb & 15;
  const int bh = swzb >> 4;
  const int b = bh >> 4, h = bh & 15;
  const size_t qkvBase = (size_t)b * 2048 * 3072 + (size_t)h * 64;

  bf16x8 aq[2][2];
#pragma unroll
  for (int fi = 0; fi < 2; fi++) {
    int qrow = qt * 128 + wave * 32 + fi * 16 + l15;
    const unsigned short* qp = QKV + qkvBase + (size_t)qrow * 3072;
#pragma unroll
    for (int kc = 0; kc < 2; kc++) {
      aq[fi][kc] = *(const bf16x8*)(qp + kc * 32 + lg * 8);
#pragma unroll
      for (int j = 0; j < 8; j++)
        aq[fi][kc][j] = (__bf16)((float)aq[fi][kc][j] * 0.125f);
    }
  }
  bf16x8 onesf;
#pragma unroll
  for (int j = 0; j < 8; j++) onesf[j] = (__bf16)1.0f;

  const unsigned short* Kg = QKV + qkvBase + 1024;
  const unsigned short* Vg = Vt + (size_t)bh * 64 * 2048;

  f32x4 o[2][4] = {};
  f32x4 ol[2] = {};
  const float M2 = 4.0f * LOG2E;

  const int srow = t >> 3;
  const int scb = (t & 7) * 16;
  const int e = (scb ^ ((srow & 7) << 4)) >> 1;

  auto stage = [&](int buf, int kt) {
    gll16(Kg + (size_t)(kt * 64 + srow) * 3072 + e, (char*)&Ks[buf][0] + t * 16);
    gll16(Kg + (size_t)(kt * 64 + srow + 32) * 3072 + e, (char*)&Ks[buf][0] + 4096 + t * 16);
    gll16(Vg + (size_t)srow * 2048 + kt * 64 + e, (char*)&Vs[buf][0] + t * 16);
    gll16(Vg + (size_t)(srow + 32) * 2048 + kt * 64 + e, (char*)&Vs[buf][0] + 4096 + t * 16);
  };

  stage(0, 0);
  __syncthreads();

  for (int kt = 0; kt < 32; kt++) {
    const int cur = kt & 1;
    if (kt < 31) stage(cur ^ 1, kt + 1);

    // S^T = K (Q/8)^T : swapped operands. Lane (l15,lg) holds q = ..+l15,
    // keys n*16 + lg*4 + r  (r = reg index).
    f32x4 s[2][4] = {};
#pragma unroll
    for (int n = 0; n < 4; n++) {
#pragma unroll
      for (int kc = 0; kc < 2; kc++) {
        int r = n * 16 + l15;  // K-fragment vector: key n*16+l15
        int cb = (kc * 64 + lg * 16) ^ ((r & 7) << 4);
        bf16x8 bk = *(const bf16x8*)&Ks[cur][r * 64 + (cb >> 1)];
        s[0][n] = __builtin_amdgcn_mfma_f32_16x16x32_bf16(bk, aq[0][kc], s[0][n], 0, 0, 0);
        s[1][n] = __builtin_amdgcn_mfma_f32_16x16x32_bf16(bk, aq[1][kc], s[1][n], 0, 0, 0);
      }
    }

    // P = exp2(s*log2e - M2) -> bf16, 4 consecutive keys packed per 8B write
#pragma unroll
    for (int fi = 0; fi < 2; fi++) {
      const int q = wave * 32 + fi * 16 + l15;
      char* prow = (char*)Ps + q * 128;
      const int qx = (q & 7) << 4;
#pragma unroll
      for (int n = 0; n < 4; n++) {
        ushort4 pw;
        pw.x = f2bf_fast(EXP2(__builtin_fmaf(s[fi][n][0], LOG2E, -M2)));
        pw.y = f2bf_fast(EXP2(__builtin_fmaf(s[fi][n][1], LOG2E, -M2)));
        pw.z = f2bf_fast(EXP2(__builtin_fmaf(s[fi][n][2], LOG2E, -M2)));
        pw.w = f2bf_fast(EXP2(__builtin_fmaf(s[fi][n][3], LOG2E, -M2)));
        *(ushort4*)(prow + ((n * 32 + lg * 8) ^ qx)) = pw;
      }
    }

    // O += P V ; l += P . 1 (ones-fragment MFMA) -- unchanged
#pragma unroll
    for (int kc = 0; kc < 2; kc++) {
      bf16x8 pa[2];
#pragma unroll
      for (int fi = 0; fi < 2; fi++) {
        int qr = wave * 32 + fi * 16 + l15;
        int cbp = (kc * 64 + lg * 16) ^ ((qr & 7) << 4);
        pa[fi] = *(const bf16x8*)&Ps[qr * 64 + (cbp >> 1)];
        ol[fi] = __builtin_amdgcn_mfma_f32_16x16x32_bf16(pa[fi], onesf, ol[fi], 0, 0, 0);
      }
#pragma unroll
      for (int n = 0; n < 4; n++) {
        int dr = n * 16 + l15;
        int cbv = (kc * 64 + lg * 16) ^ ((dr & 7) << 4);
        bf16x8 bv = *(const bf16x8*)&Vs[cur][dr * 64 + (cbv >> 1)];
        o[0][n] = __builtin_amdgcn_mfma_f32_16x16x32_bf16(pa[0], bv, o[0][n], 0, 0, 0);
        o[1][n] = __builtin_amdgcn_mfma_f32_16x16x32_bf16(pa[1], bv, o[1][n], 0, 0, 0);
      }
    }
    __syncthreads();
  }

#pragma unroll
  for (int fi = 0; fi < 2; fi++) {
    const int qrow0 = qt * 128 + wave * 32 + fi * 16;
    unsigned short* op = attnO + ((size_t)(b * 2048 + qrow0)) * 1024 + h * 64;
    float inv[4];
#pragma unroll
    for (int r = 0; r < 4; r++) inv[r] = 1.0f / ol[fi][r];
#pragma unroll
    for (int n = 0; n < 4; n++)
#pragma unroll
      for (int r = 0; r < 4; r++) {
        int q = lg * 4 + r;
        op[(size_t)q * 1024 + n * 16 + l15] = f2bf(o[fi][n][r] * inv[r]);
      }
  }
}

// ---------- launch ----------
extern "C" void kernel_launch(void* const* d_in, const int* in_sizes, int n_in,
                              void* d_out, int out_size, void* d_ws, size_t ws_size,
                              hipStream_t stream) {
  const float* x = (const float*)d_in[0];
  const float* Wq = (const float*)d_in[1];
  const float* Wk = (const float*)d_in[2];
  const float* Wv = (const float*)d_in[3];
  const float* Wo = (const float*)d_in[4];
  const float* ln1g = (const float*)d_in[5];
  const float* ln1b = (const float*)d_in[6];
  const float* ln2g = (const float*)d_in[7];
  const float* ln2b = (const float*)d_in[8];
  const float* W1 = (const float*)d_in[9];
  const float* b1 = (const float*)d_in[10];
  const float* W2 = (const float*)d_in[11];
  const float* b2 = (const float*)d_in[12];
  float* out = (float*)d_out;

  char* ws = (char*)d_ws;
  size_t off = 0;
  auto alloc = [&](size_t bytes) {
    void* p = ws + off;
    off += (bytes + 255) & ~(size_t)255;
    return p;
  };
  unsigned short* WB = (unsigned short*)alloc(3072ull * 1024 * 2);   // packed Wq|Wk|Wv
  unsigned short* WoB = (unsigned short*)alloc(1024ull * 1024 * 2);
  unsigned short* W1t = (unsigned short*)alloc(4096ull * 1024 * 2);
  unsigned short* W2t = (unsigned short*)alloc(1024ull * 4096 * 2);
  unsigned short* hb = (unsigned short*)alloc(4096ull * 1024 * 2);   // ln1 out, reused ln2 out
  unsigned short* QKV = (unsigned short*)alloc(4096ull * 3072 * 2);  // reused (with attnb) as ffnb
  unsigned short* attnb = (unsigned short*)alloc(4096ull * 1024 * 2);
  unsigned short* Vtb = (unsigned short*)alloc(32ull * 64 * 2048 * 2);
  float* x2 = (float*)alloc(4096ull * 1024 * 4);
  unsigned short* ffnb = QKV;  // 4096*4096*2 == QKV + attnb (contiguous)
  unsigned short* h2b = hb;

  cvt_weights<<<4096, 256, 0, stream>>>(Wq, Wk, Wv, Wo, WB, WoB);
  transpose_f32_bf16<<<dim3(128, 32), 256, 0, stream>>>(W1, W1t, 1024, 4096);
  transpose_f32_bf16<<<dim3(32, 128), 256, 0, stream>>>(W2, W2t, 4096, 1024);
  layernorm_bf16<<<4096, 256, 0, stream>>>(x, ln1g, ln1b, hb);
  gemm_bt<0, 128, 128><<<dim3(24, 32), 256, 0, stream>>>(hb, WB, 4096, 3072, 1024,
                                                         nullptr, QKV, nullptr, nullptr);
  vtrans<<<dim3(32, 32), 256, 0, stream>>>(QKV, Vtb);
  attn_flash<<<512, 256, 0, stream>>>(QKV, Vtb, attnb);
  gemm_bt<1, 64, 128><<<dim3(8, 64), 256, 0, stream>>>(attnb, WoB, 4096, 1024, 1024,
                                                       x2, nullptr, x, nullptr);
  layernorm_bf16<<<4096, 256, 0, stream>>>(x2, ln2g, ln2b, h2b);
  gemm_bt<2, 128, 128><<<dim3(32, 32), 256, 0, stream>>>(h2b, W1t, 4096, 4096, 1024,
                                                         nullptr, ffnb, nullptr, b1);
  gemm_bt<3, 64, 128><<<dim3(8, 64), 256, 0, stream>>>(ffnb, W2t, 4096, 1024, 4096,
                                                       out, nullptr, x2, b2);
}

// Round 15
// 249.711 us; speedup vs baseline: 1.0233x; 1.0233x over previous
//
#include <hip/hip_runtime.h>
#include <stdint.h>
#include <math.h>

// ---------- types ----------
typedef float f32x4 __attribute__((ext_vector_type(4)));
typedef __bf16 bf16x8 __attribute__((ext_vector_type(8)));

#define DEVI __device__ __forceinline__

#if __has_builtin(__builtin_amdgcn_exp2f)
#define EXP2(x) __builtin_amdgcn_exp2f(x)
#else
#define EXP2(x) exp2f(x)
#endif

#define LOG2E 1.44269504f

DEVI unsigned short f2bf(float f) {
  union { float f; unsigned int u; } c; c.f = f;
  unsigned int u = c.u;
  return (unsigned short)((u + 0x7FFFu + ((u >> 16) & 1u)) >> 16);  // RTN-even
}

// cheap round-half-up (P values only; numerator & denominator share values)
DEVI unsigned short f2bf_fast(float f) {
  union { float f; unsigned int u; } c; c.f = f;
  return (unsigned short)((c.u + 0x8000u) >> 16);
}

// async global->LDS, 16B per lane. LDS dest must be wave-uniform base + lane*16.
DEVI void gll16(const void* g, void* l) {
  __builtin_amdgcn_global_load_lds(
      (const __attribute__((address_space(1))) void*)g,
      (__attribute__((address_space(3))) void*)l,
      16, 0, 0);
}

// ---------- fp32 -> bf16: all four weight matrices in ONE launch ----------
__global__ __launch_bounds__(256) void cvt_weights(
    const float* __restrict__ Wq, const float* __restrict__ Wk,
    const float* __restrict__ Wv, const float* __restrict__ Wo,
    unsigned short* __restrict__ WB, unsigned short* __restrict__ WoB) {
  int i = blockIdx.x * 256 + threadIdx.x;  // 0 .. 4*262144-1 (float4 units)
  int seg = i >> 18;                       // 262144 float4 per matrix
  int j = i & 262143;
  const float* src = (seg == 0) ? Wq : (seg == 1) ? Wk : (seg == 2) ? Wv : Wo;
  unsigned short* dst = (seg < 3) ? WB + (size_t)seg * 1048576 : WoB;
  float4 v = ((const float4*)src)[j];
  ushort4 ov;
  ov.x = f2bf(v.x); ov.y = f2bf(v.y); ov.z = f2bf(v.z); ov.w = f2bf(v.w);
  ((ushort4*)dst)[j] = ov;
}

// ---------- fp32 R x C  ->  bf16 C x R (transpose) ----------
__global__ __launch_bounds__(256) void transpose_f32_bf16(
    const float* __restrict__ in, unsigned short* __restrict__ out, int R, int C) {
  __shared__ float tile[32][33];
  int bc = blockIdx.x * 32, br = blockIdx.y * 32;
  int tx = threadIdx.x & 31, ty = threadIdx.x >> 5;  // ty 0..7
#pragma unroll
  for (int i = 0; i < 32; i += 8)
    tile[ty + i][tx] = in[(size_t)(br + ty + i) * C + bc + tx];
  __syncthreads();
#pragma unroll
  for (int i = 0; i < 32; i += 8)
    out[(size_t)(bc + ty + i) * R + br + tx] = f2bf(tile[tx][ty + i]);
}

// ---------- V transpose: QKV[t][2048+h*64+d] -> Vt[bh][d][s] (bf16) ----------
__global__ __launch_bounds__(256) void vtrans(
    const unsigned short* __restrict__ QKV, unsigned short* __restrict__ Vt) {
  int stile = blockIdx.x;  // 0..31 (64 tokens each)
  int bh = blockIdx.y;     // 0..31
  int b = bh >> 4, h = bh & 15;
  __shared__ unsigned short tile[64][68];
  const unsigned short* src =
      QKV + ((size_t)(b * 2048 + stile * 64)) * 3072 + 2048 + h * 64;
  int t = threadIdx.x;
#pragma unroll
  for (int i = 0; i < 16; i++) {
    int e = i * 256 + t; int s = e >> 6, d = e & 63;
    tile[s][d] = src[(size_t)s * 3072 + d];
  }
  __syncthreads();
  unsigned short* dst = Vt + (size_t)bh * 64 * 2048 + stile * 64;
#pragma unroll
  for (int i = 0; i < 16; i++) {
    int e = i * 256 + t; int d = e >> 6, s = e & 63;
    dst[(size_t)d * 2048 + s] = tile[s][d];
  }
}

// ---------- LayerNorm fp32 -> bf16 ----------
__global__ __launch_bounds__(256) void layernorm_bf16(
    const float* __restrict__ x, const float* __restrict__ g,
    const float* __restrict__ be, unsigned short* __restrict__ out) {
  const int row = blockIdx.x;
  const int t = threadIdx.x;
  const float4 v = ((const float4*)(x + (size_t)row * 1024))[t];
  float s = v.x + v.y + v.z + v.w;
  float s2 = v.x * v.x + v.y * v.y + v.z * v.z + v.w * v.w;
#pragma unroll
  for (int d = 32; d > 0; d >>= 1) {
    s += __shfl_down(s, d);
    s2 += __shfl_down(s2, d);
  }
  __shared__ float ps[4], ps2[4], st[2];
  const int lane = t & 63, wave = t >> 6;
  if (lane == 0) { ps[wave] = s; ps2[wave] = s2; }
  __syncthreads();
  if (t == 0) {
    float S = ps[0] + ps[1] + ps[2] + ps[3];
    float S2 = ps2[0] + ps2[1] + ps2[2] + ps2[3];
    float mu = S * (1.0f / 1024.0f);
    float var = S2 * (1.0f / 1024.0f) - mu * mu;
    st[0] = mu; st[1] = rsqrtf(var + 1e-5f);
  }
  __syncthreads();
  float mu = st[0], inv = st[1];
  float4 gv = ((const float4*)g)[t];
  float4 bv = ((const float4*)be)[t];
  ushort4 ov;
  ov.x = f2bf((v.x - mu) * inv * gv.x + bv.x);
  ov.y = f2bf((v.y - mu) * inv * gv.y + bv.y);
  ov.z = f2bf((v.z - mu) * inv * gv.z + bv.z);
  ov.w = f2bf((v.w - mu) * inv * gv.w + bv.w);
  ((ushort4*)(out + (size_t)row * 1024))[t] = ov;
}

// exp2-based tanh-gelu: x / (1 + 2^-(c3*x + c4*x^3))
DEVI float gelu_f(float x) {
  float a = x * (2.3022082f + 0.1029432f * x * x);
  return x / (1.0f + EXP2(-a));
}

// ---------- GEMM: C[M,N] = A[M,K] * B[N,K]^T  (bf16 in, f32 acc) ----------
// Round-7 verified config: 2-phase double-buffered LDS + row-pair-packed
// XOR-swizzled LDS (0 conflicts measured). 128x128 for QKV/FFN1 (best
// measured FFN1=78.6us); 64x128 for the N=1024 GEMMs (2 blocks/CU).
// EPI 0: outB = bf16(C)
// EPI 1: outF = res + C
// EPI 2: outB = bf16(gelu(C + bias))
// EPI 3: outF = res + C + bias
template <int EPI, int TM, int TN>
__global__ __launch_bounds__(256, 4) void gemm_bt(
    const unsigned short* __restrict__ A, const unsigned short* __restrict__ B,
    int M, int N, int K, float* __restrict__ outF, unsigned short* __restrict__ outB,
    const float* __restrict__ res, const float* __restrict__ bias) {
  __shared__ __align__(16) unsigned short As[2][TM * 32];
  __shared__ __align__(16) unsigned short Bs[2][TN * 32];
  constexpr int MF = TM / 32;  // m fragments per wave
  constexpr int NF = TN / 32;  // n fragments per wave
  const int t = threadIdx.x;
  const int lane = t & 63, wave = t >> 6;
  const int wr = wave >> 1, wc = wave & 1;
  const int l15 = lane & 15, lg = lane >> 4;
  // stage-side swizzle: lane t writes LDS row r=(t>>3), phys slot s=(t&7);
  // that slot's logical content is slot sl = s ^ (r&7) of row-pair r.
  const int sl = (t & 7) ^ ((t >> 3) & 7);
  const int srow2 = ((t >> 3) << 1) + (sl >> 2);  // global row within 64-row chunk
  const int scol2 = (sl & 3) * 8;                 // elem offset within row
  // XCD-aware bijective swizzle (nwg % 8 == 0 for all our grids)
  const int gx = gridDim.x;
  const int nwg = gx * gridDim.y;
  const int orig = blockIdx.y * gx + blockIdx.x;
  const int swz = (orig & 7) * (nwg >> 3) + (orig >> 3);
  const int bx = swz % gx, by = swz / gx;
  const size_t aBase = (size_t)by * TM * K;
  const size_t bBase = (size_t)bx * TN * K;
  f32x4 acc[MF][NF] = {};

  auto stage = [&](int buf, int kt) {
#pragma unroll
    for (int i = 0; i < TM / 64; i++)
      gll16(A + aBase + (size_t)(srow2 + i * 64) * K + kt + scol2,
            (char*)&As[buf][0] + i * 4096 + t * 16);
#pragma unroll
    for (int i = 0; i < TN / 64; i++)
      gll16(B + bBase + (size_t)(srow2 + i * 64) * K + kt + scol2,
            (char*)&Bs[buf][0] + i * 4096 + t * 16);
  };

  stage(0, 0);
  __syncthreads();
  const int nk = K >> 5;
  for (int ki = 0; ki < nk; ki++) {
    const int cur = ki & 1;
    if (ki + 1 < nk) stage(cur ^ 1, (ki + 1) << 5);  // overlap with compute
    bf16x8 af[MF], bfv[NF];
#pragma unroll
    for (int m = 0; m < MF; m++) {
      const int R = wr * (TM / 2) + m * 16 + l15;
      const int r = R >> 1;
      const int ps = (((R & 1) << 2) | lg) ^ (r & 7);
      af[m] = *(const bf16x8*)&As[cur][r * 64 + ps * 8];
    }
#pragma unroll
    for (int n = 0; n < NF; n++) {
      const int R = wc * (TN / 2) + n * 16 + l15;
      const int r = R >> 1;
      const int ps = (((R & 1) << 2) | lg) ^ (r & 7);
      bfv[n] = *(const bf16x8*)&Bs[cur][r * 64 + ps * 8];
    }
#pragma unroll
    for (int m = 0; m < MF; m++)
#pragma unroll
      for (int n = 0; n < NF; n++)
        acc[m][n] = __builtin_amdgcn_mfma_f32_16x16x32_bf16(af[m], bfv[n], acc[m][n], 0, 0, 0);
    __syncthreads();  // drains prefetch (vmcnt 0) + protects cur for next overwrite
  }
  const int rowB = by * TM + wr * (TM / 2);
  const int colB = bx * TN + wc * (TN / 2);
#pragma unroll
  for (int m = 0; m < MF; m++) {
#pragma unroll
    for (int n = 0; n < NF; n++) {
#pragma unroll
      for (int r = 0; r < 4; r++) {
        int gm = rowB + m * 16 + lg * 4 + r;
        int gn = colB + n * 16 + l15;
        float c = acc[m][n][r];
        size_t idx = (size_t)gm * N + gn;
        if (EPI == 0) {
          outB[idx] = f2bf(c);
        } else if (EPI == 1) {
          outF[idx] = res[idx] + c;
        } else if (EPI == 2) {
          outB[idx] = f2bf(gelu_f(c + bias[gn]));
        } else {
          outF[idx] = res[idx] + c + bias[gn];
        }
      }
    }
  }
}

// ---------- flash attention, static-max softmax, QBLK=128 (verified r9) ----
// 512 blocks; XCD-swizzled to (bh, qtile); 4 waves x 32 q-rows x 64 keys/tile.
// K/V double-buffered in LDS; Q pre-scaled by 0.125 (exact in bf16).
// Softmax uses FIXED shift M=4 (exact by shift-invariance; |s| << 87).
// Denominator via ones-fragment MFMA on the same rounded-bf16 P.
// NOTE r14 lesson: packed 8B P-writes via swapped-operand QK^T introduce
// write-side bank conflicts (XOR bit-overlap at bank bit 2) -- keep the
// scalar b16 stores (measured 0 conflicts).
__global__ __launch_bounds__(256) void attn_flash(
    const unsigned short* __restrict__ QKV, const unsigned short* __restrict__ Vt,
    unsigned short* __restrict__ attnO) {
  __shared__ __align__(16) unsigned short Ks[2][64 * 64];
  __shared__ __align__(16) unsigned short Vs[2][64 * 64];
  __shared__ __align__(16) unsigned short Ps[128 * 64];
  const int t = threadIdx.x;
  const int lane = t & 63, wave = t >> 6;
  const int l15 = lane & 15, lg = lane >> 4;
  const int bid = blockIdx.x;
  const int swzb = (bid & 7) * 64 + (bid >> 3);
  const int qt = swzb & 15;
  const int bh = swzb >> 4;
  const int b = bh >> 4, h = bh & 15;
  const size_t qkvBase = (size_t)b * 2048 * 3072 + (size_t)h * 64;

  bf16x8 aq[2][2];
#pragma unroll
  for (int fi = 0; fi < 2; fi++) {
    int qrow = qt * 128 + wave * 32 + fi * 16 + l15;
    const unsigned short* qp = QKV + qkvBase + (size_t)qrow * 3072;
#pragma unroll
    for (int kc = 0; kc < 2; kc++) {
      aq[fi][kc] = *(const bf16x8*)(qp + kc * 32 + lg * 8);
#pragma unroll
      for (int j = 0; j < 8; j++)
        aq[fi][kc][j] = (__bf16)((float)aq[fi][kc][j] * 0.125f);
    }
  }
  bf16x8 onesf;
#pragma unroll
  for (int j = 0; j < 8; j++) onesf[j] = (__bf16)1.0f;

  const unsigned short* Kg = QKV + qkvBase + 1024;
  const unsigned short* Vg = Vt + (size_t)bh * 64 * 2048;

  f32x4 o[2][4] = {};
  f32x4 ol[2] = {};
  const float M2 = 4.0f * LOG2E;

  const int srow = t >> 3;
  const int scb = (t & 7) * 16;
  const int e = (scb ^ ((srow & 7) << 4)) >> 1;

  auto stage = [&](int buf, int kt) {
    gll16(Kg + (size_t)(kt * 64 + srow) * 3072 + e, (char*)&Ks[buf][0] + t * 16);
    gll16(Kg + (size_t)(kt * 64 + srow + 32) * 3072 + e, (char*)&Ks[buf][0] + 4096 + t * 16);
    gll16(Vg + (size_t)srow * 2048 + kt * 64 + e, (char*)&Vs[buf][0] + t * 16);
    gll16(Vg + (size_t)(srow + 32) * 2048 + kt * 64 + e, (char*)&Vs[buf][0] + 4096 + t * 16);
  };

  stage(0, 0);
  __syncthreads();

  for (int kt = 0; kt < 32; kt++) {
    const int cur = kt & 1;
    if (kt < 31) stage(cur ^ 1, kt + 1);

    f32x4 s[2][4] = {};
#pragma unroll
    for (int n = 0; n < 4; n++) {
#pragma unroll
      for (int kc = 0; kc < 2; kc++) {
        int r = n * 16 + l15;
        int cb = (kc * 64 + lg * 16) ^ ((r & 7) << 4);
        bf16x8 bk = *(const bf16x8*)&Ks[cur][r * 64 + (cb >> 1)];
        s[0][n] = __builtin_amdgcn_mfma_f32_16x16x32_bf16(aq[0][kc], bk, s[0][n], 0, 0, 0);
        s[1][n] = __builtin_amdgcn_mfma_f32_16x16x32_bf16(aq[1][kc], bk, s[1][n], 0, 0, 0);
      }
    }

#pragma unroll
    for (int fi = 0; fi < 2; fi++) {
      const int q0 = wave * 32 + fi * 16 + lg * 4;
#pragma unroll
      for (int n = 0; n < 4; n++)
#pragma unroll
        for (int r = 0; r < 4; r++) {
          int q = q0 + r;
          int cb = ((n * 16 + l15) * 2) ^ ((q & 7) << 4);
          float p = EXP2(__builtin_fmaf(s[fi][n][r], LOG2E, -M2));
          Ps[q * 64 + (cb >> 1)] = f2bf_fast(p);
        }
    }

#pragma unroll
    for (int kc = 0; kc < 2; kc++) {
      bf16x8 pa[2];
#pragma unroll
      for (int fi = 0; fi < 2; fi++) {
        int qr = wave * 32 + fi * 16 + l15;
        int cbp = (kc * 64 + lg * 16) ^ ((qr & 7) << 4);
        pa[fi] = *(const bf16x8*)&Ps[qr * 64 + (cbp >> 1)];
        ol[fi] = __builtin_amdgcn_mfma_f32_16x16x32_bf16(pa[fi], onesf, ol[fi], 0, 0, 0);
      }
#pragma unroll
      for (int n = 0; n < 4; n++) {
        int dr = n * 16 + l15;
        int cbv = (kc * 64 + lg * 16) ^ ((dr & 7) << 4);
        bf16x8 bv = *(const bf16x8*)&Vs[cur][dr * 64 + (cbv >> 1)];
        o[0][n] = __builtin_amdgcn_mfma_f32_16x16x32_bf16(pa[0], bv, o[0][n], 0, 0, 0);
        o[1][n] = __builtin_amdgcn_mfma_f32_16x16x32_bf16(pa[1], bv, o[1][n], 0, 0, 0);
      }
    }
    __syncthreads();
  }

#pragma unroll
  for (int fi = 0; fi < 2; fi++) {
    const int qrow0 = qt * 128 + wave * 32 + fi * 16;
    unsigned short* op = attnO + ((size_t)(b * 2048 + qrow0)) * 1024 + h * 64;
    float inv[4];
#pragma unroll
    for (int r = 0; r < 4; r++) inv[r] = 1.0f / ol[fi][r];
#pragma unroll
    for (int n = 0; n < 4; n++)
#pragma unroll
      for (int r = 0; r < 4; r++) {
        int q = lg * 4 + r;
        op[(size_t)q * 1024 + n * 16 + l15] = f2bf(o[fi][n][r] * inv[r]);
      }
  }
}

// ---------- launch ----------
extern "C" void kernel_launch(void* const* d_in, const int* in_sizes, int n_in,
                              void* d_out, int out_size, void* d_ws, size_t ws_size,
                              hipStream_t stream) {
  const float* x = (const float*)d_in[0];
  const float* Wq = (const float*)d_in[1];
  const float* Wk = (const float*)d_in[2];
  const float* Wv = (const float*)d_in[3];
  const float* Wo = (const float*)d_in[4];
  const float* ln1g = (const float*)d_in[5];
  const float* ln1b = (const float*)d_in[6];
  const float* ln2g = (const float*)d_in[7];
  const float* ln2b = (const float*)d_in[8];
  const float* W1 = (const float*)d_in[9];
  const float* b1 = (const float*)d_in[10];
  const float* W2 = (const float*)d_in[11];
  const float* b2 = (const float*)d_in[12];
  float* out = (float*)d_out;

  char* ws = (char*)d_ws;
  size_t off = 0;
  auto alloc = [&](size_t bytes) {
    void* p = ws + off;
    off += (bytes + 255) & ~(size_t)255;
    return p;
  };
  unsigned short* WB = (unsigned short*)alloc(3072ull * 1024 * 2);   // packed Wq|Wk|Wv
  unsigned short* WoB = (unsigned short*)alloc(1024ull * 1024 * 2);
  unsigned short* W1t = (unsigned short*)alloc(4096ull * 1024 * 2);
  unsigned short* W2t = (unsigned short*)alloc(1024ull * 4096 * 2);
  unsigned short* hb = (unsigned short*)alloc(4096ull * 1024 * 2);   // ln1 out, reused ln2 out
  unsigned short* QKV = (unsigned short*)alloc(4096ull * 3072 * 2);  // reused (with attnb) as ffnb
  unsigned short* attnb = (unsigned short*)alloc(4096ull * 1024 * 2);
  unsigned short* Vtb = (unsigned short*)alloc(32ull * 64 * 2048 * 2);
  float* x2 = (float*)alloc(4096ull * 1024 * 4);
  unsigned short* ffnb = QKV;  // 4096*4096*2 == QKV + attnb (contiguous)
  unsigned short* h2b = hb;

  cvt_weights<<<4096, 256, 0, stream>>>(Wq, Wk, Wv, Wo, WB, WoB);
  transpose_f32_bf16<<<dim3(128, 32), 256, 0, stream>>>(W1, W1t, 1024, 4096);
  transpose_f32_bf16<<<dim3(32, 128), 256, 0, stream>>>(W2, W2t, 4096, 1024);
  layernorm_bf16<<<4096, 256, 0, stream>>>(x, ln1g, ln1b, hb);
  gemm_bt<0, 128, 128><<<dim3(24, 32), 256, 0, stream>>>(hb, WB, 4096, 3072, 1024,
                                                         nullptr, QKV, nullptr, nullptr);
  vtrans<<<dim3(32, 32), 256, 0, stream>>>(QKV, Vtb);
  attn_flash<<<512, 256, 0, stream>>>(QKV, Vtb, attnb);
  gemm_bt<1, 64, 128><<<dim3(8, 64), 256, 0, stream>>>(attnb, WoB, 4096, 1024, 1024,
                                                       x2, nullptr, x, nullptr);
  layernorm_bf16<<<4096, 256, 0, stream>>>(x2, ln2g, ln2b, h2b);
  gemm_bt<2, 128, 128><<<dim3(32, 32), 256, 0, stream>>>(h2b, W1t, 4096, 4096, 1024,
                                                         nullptr, ffnb, nullptr, b1);
  gemm_bt<3, 64, 128><<<dim3(8, 64), 256, 0, stream>>>(ffnb, W2t, 4096, 1024, 4096,
                                                       out, nullptr, x2, b2);
}

// Round 16
// 246.328 us; speedup vs baseline: 1.0373x; 1.0137x over previous
//
#include <hip/hip_runtime.h>
#include <stdint.h>
#include <math.h>

// ---------- types ----------
typedef float f32x4 __attribute__((ext_vector_type(4)));
typedef __bf16 bf16x8 __attribute__((ext_vector_type(8)));

#define DEVI __device__ __forceinline__

#if __has_builtin(__builtin_amdgcn_exp2f)
#define EXP2(x) __builtin_amdgcn_exp2f(x)
#else
#define EXP2(x) exp2f(x)
#endif

#define LOG2E 1.44269504f

DEVI unsigned short f2bf(float f) {
  union { float f; unsigned int u; } c; c.f = f;
  unsigned int u = c.u;
  return (unsigned short)((u + 0x7FFFu + ((u >> 16) & 1u)) >> 16);  // RTN-even
}

// cheap round-half-up (P values only; numerator & denominator share values)
DEVI unsigned short f2bf_fast(float f) {
  union { float f; unsigned int u; } c; c.f = f;
  return (unsigned short)((c.u + 0x8000u) >> 16);
}

// async global->LDS, 16B per lane. LDS dest must be wave-uniform base + lane*16.
DEVI void gll16(const void* g, void* l) {
  __builtin_amdgcn_global_load_lds(
      (const __attribute__((address_space(1))) void*)g,
      (__attribute__((address_space(3))) void*)l,
      16, 0, 0);
}

// ---------- fp32 -> bf16: all four weight matrices in ONE launch ----------
__global__ __launch_bounds__(256) void cvt_weights(
    const float* __restrict__ Wq, const float* __restrict__ Wk,
    const float* __restrict__ Wv, const float* __restrict__ Wo,
    unsigned short* __restrict__ WB, unsigned short* __restrict__ WoB) {
  int i = blockIdx.x * 256 + threadIdx.x;  // 0 .. 4*262144-1 (float4 units)
  int seg = i >> 18;                       // 262144 float4 per matrix
  int j = i & 262143;
  const float* src = (seg == 0) ? Wq : (seg == 1) ? Wk : (seg == 2) ? Wv : Wo;
  unsigned short* dst = (seg < 3) ? WB + (size_t)seg * 1048576 : WoB;
  float4 v = ((const float4*)src)[j];
  ushort4 ov;
  ov.x = f2bf(v.x); ov.y = f2bf(v.y); ov.z = f2bf(v.z); ov.w = f2bf(v.w);
  ((ushort4*)dst)[j] = ov;
}

// ---------- fp32 R x C  ->  bf16 C x R (transpose) ----------
__global__ __launch_bounds__(256) void transpose_f32_bf16(
    const float* __restrict__ in, unsigned short* __restrict__ out, int R, int C) {
  __shared__ float tile[32][33];
  int bc = blockIdx.x * 32, br = blockIdx.y * 32;
  int tx = threadIdx.x & 31, ty = threadIdx.x >> 5;  // ty 0..7
#pragma unroll
  for (int i = 0; i < 32; i += 8)
    tile[ty + i][tx] = in[(size_t)(br + ty + i) * C + bc + tx];
  __syncthreads();
#pragma unroll
  for (int i = 0; i < 32; i += 8)
    out[(size_t)(bc + ty + i) * R + br + tx] = f2bf(tile[tx][ty + i]);
}

// ---------- V transpose: QKV[t][2048+h*64+d] -> Vt[bh][d][s] (bf16) ----------
__global__ __launch_bounds__(256) void vtrans(
    const unsigned short* __restrict__ QKV, unsigned short* __restrict__ Vt) {
  int stile = blockIdx.x;  // 0..31 (64 tokens each)
  int bh = blockIdx.y;     // 0..31
  int b = bh >> 4, h = bh & 15;
  __shared__ unsigned short tile[64][68];
  const unsigned short* src =
      QKV + ((size_t)(b * 2048 + stile * 64)) * 3072 + 2048 + h * 64;
  int t = threadIdx.x;
#pragma unroll
  for (int i = 0; i < 16; i++) {
    int e = i * 256 + t; int s = e >> 6, d = e & 63;
    tile[s][d] = src[(size_t)s * 3072 + d];
  }
  __syncthreads();
  unsigned short* dst = Vt + (size_t)bh * 64 * 2048 + stile * 64;
#pragma unroll
  for (int i = 0; i < 16; i++) {
    int e = i * 256 + t; int d = e >> 6, s = e & 63;
    dst[(size_t)d * 2048 + s] = tile[s][d];
  }
}

// ---------- LayerNorm fp32 -> bf16 ----------
__global__ __launch_bounds__(256) void layernorm_bf16(
    const float* __restrict__ x, const float* __restrict__ g,
    const float* __restrict__ be, unsigned short* __restrict__ out) {
  const int row = blockIdx.x;
  const int t = threadIdx.x;
  const float4 v = ((const float4*)(x + (size_t)row * 1024))[t];
  float s = v.x + v.y + v.z + v.w;
  float s2 = v.x * v.x + v.y * v.y + v.z * v.z + v.w * v.w;
#pragma unroll
  for (int d = 32; d > 0; d >>= 1) {
    s += __shfl_down(s, d);
    s2 += __shfl_down(s2, d);
  }
  __shared__ float ps[4], ps2[4], st[2];
  const int lane = t & 63, wave = t >> 6;
  if (lane == 0) { ps[wave] = s; ps2[wave] = s2; }
  __syncthreads();
  if (t == 0) {
    float S = ps[0] + ps[1] + ps[2] + ps[3];
    float S2 = ps2[0] + ps2[1] + ps2[2] + ps2[3];
    float mu = S * (1.0f / 1024.0f);
    float var = S2 * (1.0f / 1024.0f) - mu * mu;
    st[0] = mu; st[1] = rsqrtf(var + 1e-5f);
  }
  __syncthreads();
  float mu = st[0], inv = st[1];
  float4 gv = ((const float4*)g)[t];
  float4 bv = ((const float4*)be)[t];
  ushort4 ov;
  ov.x = f2bf((v.x - mu) * inv * gv.x + bv.x);
  ov.y = f2bf((v.y - mu) * inv * gv.y + bv.y);
  ov.z = f2bf((v.z - mu) * inv * gv.z + bv.z);
  ov.w = f2bf((v.w - mu) * inv * gv.w + bv.w);
  ((ushort4*)(out + (size_t)row * 1024))[t] = ov;
}

// exp2-based tanh-gelu: x / (1 + 2^-(c3*x + c4*x^3))
DEVI float gelu_f(float x) {
  float a = x * (2.3022082f + 0.1029432f * x * x);
  return x / (1.0f + EXP2(-a));
}

// ---------- GEMM: C[M,N] = A[M,K] * B[N,K]^T  (bf16 in, f32 acc) ----------
// Round-7 verified config: 2-phase double-buffered LDS + row-pair-packed
// XOR-swizzled LDS (0 conflicts measured). 128x128 for QKV/FFN1; 64x128
// for the N=1024 GEMMs (2 blocks/CU).
// EPI 0: outB = bf16(C)
// EPI 1: outF = res + C
// EPI 2: outB = bf16(gelu(C + bias))
// EPI 3: outF = res + C + bias
template <int EPI, int TM, int TN>
__global__ __launch_bounds__(256, 4) void gemm_bt(
    const unsigned short* __restrict__ A, const unsigned short* __restrict__ B,
    int M, int N, int K, float* __restrict__ outF, unsigned short* __restrict__ outB,
    const float* __restrict__ res, const float* __restrict__ bias) {
  __shared__ __align__(16) unsigned short As[2][TM * 32];
  __shared__ __align__(16) unsigned short Bs[2][TN * 32];
  constexpr int MF = TM / 32;  // m fragments per wave
  constexpr int NF = TN / 32;  // n fragments per wave
  const int t = threadIdx.x;
  const int lane = t & 63, wave = t >> 6;
  const int wr = wave >> 1, wc = wave & 1;
  const int l15 = lane & 15, lg = lane >> 4;
  // stage-side swizzle: lane t writes LDS row r=(t>>3), phys slot s=(t&7);
  // that slot's logical content is slot sl = s ^ (r&7) of row-pair r.
  const int sl = (t & 7) ^ ((t >> 3) & 7);
  const int srow2 = ((t >> 3) << 1) + (sl >> 2);  // global row within 64-row chunk
  const int scol2 = (sl & 3) * 8;                 // elem offset within row
  // XCD-aware bijective swizzle (nwg % 8 == 0 for all our grids)
  const int gx = gridDim.x;
  const int nwg = gx * gridDim.y;
  const int orig = blockIdx.y * gx + blockIdx.x;
  const int swz = (orig & 7) * (nwg >> 3) + (orig >> 3);
  const int bx = swz % gx, by = swz / gx;
  const size_t aBase = (size_t)by * TM * K;
  const size_t bBase = (size_t)bx * TN * K;
  f32x4 acc[MF][NF] = {};

  auto stage = [&](int buf, int kt) {
#pragma unroll
    for (int i = 0; i < TM / 64; i++)
      gll16(A + aBase + (size_t)(srow2 + i * 64) * K + kt + scol2,
            (char*)&As[buf][0] + i * 4096 + t * 16);
#pragma unroll
    for (int i = 0; i < TN / 64; i++)
      gll16(B + bBase + (size_t)(srow2 + i * 64) * K + kt + scol2,
            (char*)&Bs[buf][0] + i * 4096 + t * 16);
  };

  stage(0, 0);
  __syncthreads();
  const int nk = K >> 5;
  for (int ki = 0; ki < nk; ki++) {
    const int cur = ki & 1;
    if (ki + 1 < nk) stage(cur ^ 1, (ki + 1) << 5);  // overlap with compute
    bf16x8 af[MF], bfv[NF];
#pragma unroll
    for (int m = 0; m < MF; m++) {
      const int R = wr * (TM / 2) + m * 16 + l15;
      const int r = R >> 1;
      const int ps = (((R & 1) << 2) | lg) ^ (r & 7);
      af[m] = *(const bf16x8*)&As[cur][r * 64 + ps * 8];
    }
#pragma unroll
    for (int n = 0; n < NF; n++) {
      const int R = wc * (TN / 2) + n * 16 + l15;
      const int r = R >> 1;
      const int ps = (((R & 1) << 2) | lg) ^ (r & 7);
      bfv[n] = *(const bf16x8*)&Bs[cur][r * 64 + ps * 8];
    }
#pragma unroll
    for (int m = 0; m < MF; m++)
#pragma unroll
      for (int n = 0; n < NF; n++)
        acc[m][n] = __builtin_amdgcn_mfma_f32_16x16x32_bf16(af[m], bfv[n], acc[m][n], 0, 0, 0);
    __syncthreads();  // drains prefetch (vmcnt 0) + protects cur for next overwrite
  }
  const int rowB = by * TM + wr * (TM / 2);
  const int colB = bx * TN + wc * (TN / 2);
#pragma unroll
  for (int m = 0; m < MF; m++) {
#pragma unroll
    for (int n = 0; n < NF; n++) {
#pragma unroll
      for (int r = 0; r < 4; r++) {
        int gm = rowB + m * 16 + lg * 4 + r;
        int gn = colB + n * 16 + l15;
        float c = acc[m][n][r];
        size_t idx = (size_t)gm * N + gn;
        if (EPI == 0) {
          outB[idx] = f2bf(c);
        } else if (EPI == 1) {
          outF[idx] = res[idx] + c;
        } else if (EPI == 2) {
          outB[idx] = f2bf(gelu_f(c + bias[gn]));
        } else {
          outF[idx] = res[idx] + c + bias[gn];
        }
      }
    }
  }
}

// ---------- flash attention, static-max softmax, QBLK=128, 8 waves --------
// Round 16: same verified r13 structure/tile, but 512-thread blocks:
// 8 waves x 16 q-rows (wave owns rows [16w,16w+16) of the 128-row tile;
// the old fi loop becomes the wave dimension). Grid 512 blocks = 2/CU;
// 8 waves/block -> 16 waves/CU (was 8) for latency hiding. Staging: 512
// threads cover each 8KB K/V buffer with ONE gll16 per thread (srow=t>>3
// now spans 0..63; per-wave source pattern unchanged -> same 0-conflict
// layout). K/V/Ps LDS layouts byte-identical to r13.
__global__ __launch_bounds__(512) void attn_flash(
    const unsigned short* __restrict__ QKV, const unsigned short* __restrict__ Vt,
    unsigned short* __restrict__ attnO) {
  __shared__ __align__(16) unsigned short Ks[2][64 * 64];
  __shared__ __align__(16) unsigned short Vs[2][64 * 64];
  __shared__ __align__(16) unsigned short Ps[128 * 64];
  const int t = threadIdx.x;
  const int lane = t & 63, wave = t >> 6;  // wave 0..7
  const int l15 = lane & 15, lg = lane >> 4;
  const int bid = blockIdx.x;
  const int swzb = (bid & 7) * 64 + (bid >> 3);
  const int qt = swzb & 15;
  const int bh = swzb >> 4;
  const int b = bh >> 4, h = bh & 15;
  const size_t qkvBase = (size_t)b * 2048 * 3072 + (size_t)h * 64;

  // Q fragment for this wave's 16 rows, pre-scaled by 1/8 (exact in bf16)
  bf16x8 aq[2];
  {
    int qrow = qt * 128 + wave * 16 + l15;
    const unsigned short* qp = QKV + qkvBase + (size_t)qrow * 3072;
#pragma unroll
    for (int kc = 0; kc < 2; kc++) {
      aq[kc] = *(const bf16x8*)(qp + kc * 32 + lg * 8);
#pragma unroll
      for (int j = 0; j < 8; j++)
        aq[kc][j] = (__bf16)((float)aq[kc][j] * 0.125f);
    }
  }
  bf16x8 onesf;
#pragma unroll
  for (int j = 0; j < 8; j++) onesf[j] = (__bf16)1.0f;

  const unsigned short* Kg = QKV + qkvBase + 1024;
  const unsigned short* Vg = Vt + (size_t)bh * 64 * 2048;

  f32x4 o[4] = {};
  f32x4 ol = {};
  const float M2 = 4.0f * LOG2E;

  const int srow = t >> 3;                       // 0..63 (512 threads)
  const int scb = (t & 7) * 16;
  const int e = (scb ^ ((srow & 7) << 4)) >> 1;  // pre-swizzled source elem

  auto stage = [&](int buf, int kt) {
    gll16(Kg + (size_t)(kt * 64 + srow) * 3072 + e, (char*)&Ks[buf][0] + t * 16);
    gll16(Vg + (size_t)srow * 2048 + kt * 64 + e, (char*)&Vs[buf][0] + t * 16);
  };

  stage(0, 0);
  __syncthreads();

  for (int kt = 0; kt < 32; kt++) {
    const int cur = kt & 1;
    if (kt < 31) stage(cur ^ 1, kt + 1);  // overlap next-tile loads with compute

    // S = (Q/8) K^T for this wave's 16 q-rows
    f32x4 s[4] = {};
#pragma unroll
    for (int n = 0; n < 4; n++) {
#pragma unroll
      for (int kc = 0; kc < 2; kc++) {
        int r = n * 16 + l15;
        int cb = (kc * 64 + lg * 16) ^ ((r & 7) << 4);
        bf16x8 bk = *(const bf16x8*)&Ks[cur][r * 64 + (cb >> 1)];
        s[n] = __builtin_amdgcn_mfma_f32_16x16x32_bf16(aq[kc], bk, s[n], 0, 0, 0);
      }
    }

    // P = exp2(s*log2e - M2) -> bf16 (cheap round) -> swizzled LDS
    const int q0 = wave * 16 + lg * 4;
#pragma unroll
    for (int n = 0; n < 4; n++)
#pragma unroll
      for (int r = 0; r < 4; r++) {
        int q = q0 + r;
        int cb = ((n * 16 + l15) * 2) ^ ((q & 7) << 4);
        float p = EXP2(__builtin_fmaf(s[n][r], LOG2E, -M2));
        Ps[q * 64 + (cb >> 1)] = f2bf_fast(p);
      }

    // O += P V ; l += P . 1 (ones-fragment MFMA)
#pragma unroll
    for (int kc = 0; kc < 2; kc++) {
      int qr = wave * 16 + l15;
      int cbp = (kc * 64 + lg * 16) ^ ((qr & 7) << 4);
      bf16x8 pa = *(const bf16x8*)&Ps[qr * 64 + (cbp >> 1)];
      ol = __builtin_amdgcn_mfma_f32_16x16x32_bf16(pa, onesf, ol, 0, 0, 0);
#pragma unroll
      for (int n = 0; n < 4; n++) {
        int dr = n * 16 + l15;
        int cbv = (kc * 64 + lg * 16) ^ ((dr & 7) << 4);
        bf16x8 bv = *(const bf16x8*)&Vs[cur][dr * 64 + (cbv >> 1)];
        o[n] = __builtin_amdgcn_mfma_f32_16x16x32_bf16(pa, bv, o[n], 0, 0, 0);
      }
    }
    __syncthreads();  // drains staged loads + protects buffers/Ps
  }

  // epilogue: O / l, store bf16
  const int qrow0 = qt * 128 + wave * 16;
  unsigned short* op = attnO + ((size_t)(b * 2048 + qrow0)) * 1024 + h * 64;
  float inv[4];
#pragma unroll
  for (int r = 0; r < 4; r++) inv[r] = 1.0f / ol[r];
#pragma unroll
  for (int n = 0; n < 4; n++)
#pragma unroll
    for (int r = 0; r < 4; r++) {
      int q = lg * 4 + r;
      op[(size_t)q * 1024 + n * 16 + l15] = f2bf(o[n][r] * inv[r]);
    }
}

// ---------- launch ----------
extern "C" void kernel_launch(void* const* d_in, const int* in_sizes, int n_in,
                              void* d_out, int out_size, void* d_ws, size_t ws_size,
                              hipStream_t stream) {
  const float* x = (const float*)d_in[0];
  const float* Wq = (const float*)d_in[1];
  const float* Wk = (const float*)d_in[2];
  const float* Wv = (const float*)d_in[3];
  const float* Wo = (const float*)d_in[4];
  const float* ln1g = (const float*)d_in[5];
  const float* ln1b = (const float*)d_in[6];
  const float* ln2g = (const float*)d_in[7];
  const float* ln2b = (const float*)d_in[8];
  const float* W1 = (const float*)d_in[9];
  const float* b1 = (const float*)d_in[10];
  const float* W2 = (const float*)d_in[11];
  const float* b2 = (const float*)d_in[12];
  float* out = (float*)d_out;

  char* ws = (char*)d_ws;
  size_t off = 0;
  auto alloc = [&](size_t bytes) {
    void* p = ws + off;
    off += (bytes + 255) & ~(size_t)255;
    return p;
  };
  unsigned short* WB = (unsigned short*)alloc(3072ull * 1024 * 2);   // packed Wq|Wk|Wv
  unsigned short* WoB = (unsigned short*)alloc(1024ull * 1024 * 2);
  unsigned short* W1t = (unsigned short*)alloc(4096ull * 1024 * 2);
  unsigned short* W2t = (unsigned short*)alloc(1024ull * 4096 * 2);
  unsigned short* hb = (unsigned short*)alloc(4096ull * 1024 * 2);   // ln1 out, reused ln2 out
  unsigned short* QKV = (unsigned short*)alloc(4096ull * 3072 * 2);  // reused (with attnb) as ffnb
  unsigned short* attnb = (unsigned short*)alloc(4096ull * 1024 * 2);
  unsigned short* Vtb = (unsigned short*)alloc(32ull * 64 * 2048 * 2);
  float* x2 = (float*)alloc(4096ull * 1024 * 4);
  unsigned short* ffnb = QKV;  // 4096*4096*2 == QKV + attnb (contiguous)
  unsigned short* h2b = hb;

  cvt_weights<<<4096, 256, 0, stream>>>(Wq, Wk, Wv, Wo, WB, WoB);
  transpose_f32_bf16<<<dim3(128, 32), 256, 0, stream>>>(W1, W1t, 1024, 4096);
  transpose_f32_bf16<<<dim3(32, 128), 256, 0, stream>>>(W2, W2t, 4096, 1024);
  layernorm_bf16<<<4096, 256, 0, stream>>>(x, ln1g, ln1b, hb);
  gemm_bt<0, 128, 128><<<dim3(24, 32), 256, 0, stream>>>(hb, WB, 4096, 3072, 1024,
                                                         nullptr, QKV, nullptr, nullptr);
  vtrans<<<dim3(32, 32), 256, 0, stream>>>(QKV, Vtb);
  attn_flash<<<512, 512, 0, stream>>>(QKV, Vtb, attnb);
  gemm_bt<1, 64, 128><<<dim3(8, 64), 256, 0, stream>>>(attnb, WoB, 4096, 1024, 1024,
                                                       x2, nullptr, x, nullptr);
  layernorm_bf16<<<4096, 256, 0, stream>>>(x2, ln2g, ln2b, h2b);
  gemm_bt<2, 128, 128><<<dim3(32, 32), 256, 0, stream>>>(h2b, W1t, 4096, 4096, 1024,
                                                         nullptr, ffnb, nullptr, b1);
  gemm_bt<3, 64, 128><<<dim3(8, 64), 256, 0, stream>>>(ffnb, W2t, 4096, 1024, 4096,
                                                       out, nullptr, x2, b2);
}

// Round 17
// 245.684 us; speedup vs baseline: 1.0400x; 1.0026x over previous
//
#include <hip/hip_runtime.h>
#include <stdint.h>
#include <math.h>

// ---------- types ----------
typedef float f32x4 __attribute__((ext_vector_type(4)));
typedef __bf16 bf16x8 __attribute__((ext_vector_type(8)));

#define DEVI __device__ __forceinline__

#if __has_builtin(__builtin_amdgcn_exp2f)
#define EXP2(x) __builtin_amdgcn_exp2f(x)
#else
#define EXP2(x) exp2f(x)
#endif

#define LOG2E 1.44269504f

DEVI unsigned short f2bf(float f) {
  union { float f; unsigned int u; } c; c.f = f;
  unsigned int u = c.u;
  return (unsigned short)((u + 0x7FFFu + ((u >> 16) & 1u)) >> 16);  // RTN-even
}

// cheap round-half-up (P values only; numerator & denominator share values)
DEVI unsigned short f2bf_fast(float f) {
  union { float f; unsigned int u; } c; c.f = f;
  return (unsigned short)((c.u + 0x8000u) >> 16);
}

// async global->LDS, 16B per lane. LDS dest must be wave-uniform base + lane*16.
DEVI void gll16(const void* g, void* l) {
  __builtin_amdgcn_global_load_lds(
      (const __attribute__((address_space(1))) void*)g,
      (__attribute__((address_space(3))) void*)l,
      16, 0, 0);
}

// ---------- fp32 -> bf16: all four weight matrices in ONE launch ----------
__global__ __launch_bounds__(256) void cvt_weights(
    const float* __restrict__ Wq, const float* __restrict__ Wk,
    const float* __restrict__ Wv, const float* __restrict__ Wo,
    unsigned short* __restrict__ WB, unsigned short* __restrict__ WoB) {
  int i = blockIdx.x * 256 + threadIdx.x;  // 0 .. 4*262144-1 (float4 units)
  int seg = i >> 18;                       // 262144 float4 per matrix
  int j = i & 262143;
  const float* src = (seg == 0) ? Wq : (seg == 1) ? Wk : (seg == 2) ? Wv : Wo;
  unsigned short* dst = (seg < 3) ? WB + (size_t)seg * 1048576 : WoB;
  float4 v = ((const float4*)src)[j];
  ushort4 ov;
  ov.x = f2bf(v.x); ov.y = f2bf(v.y); ov.z = f2bf(v.z); ov.w = f2bf(v.w);
  ((ushort4*)dst)[j] = ov;
}

// ---------- fp32 R x C  ->  bf16 C x R (transpose) ----------
__global__ __launch_bounds__(256) void transpose_f32_bf16(
    const float* __restrict__ in, unsigned short* __restrict__ out, int R, int C) {
  __shared__ float tile[32][33];
  int bc = blockIdx.x * 32, br = blockIdx.y * 32;
  int tx = threadIdx.x & 31, ty = threadIdx.x >> 5;  // ty 0..7
#pragma unroll
  for (int i = 0; i < 32; i += 8)
    tile[ty + i][tx] = in[(size_t)(br + ty + i) * C + bc + tx];
  __syncthreads();
#pragma unroll
  for (int i = 0; i < 32; i += 8)
    out[(size_t)(bc + ty + i) * R + br + tx] = f2bf(tile[tx][ty + i]);
}

// ---------- V transpose: QKV[t][2048+h*64+d] -> Vt[bh][d][s] (bf16) ----------
__global__ __launch_bounds__(256) void vtrans(
    const unsigned short* __restrict__ QKV, unsigned short* __restrict__ Vt) {
  int stile = blockIdx.x;  // 0..31 (64 tokens each)
  int bh = blockIdx.y;     // 0..31
  int b = bh >> 4, h = bh & 15;
  __shared__ unsigned short tile[64][68];
  const unsigned short* src =
      QKV + ((size_t)(b * 2048 + stile * 64)) * 3072 + 2048 + h * 64;
  int t = threadIdx.x;
#pragma unroll
  for (int i = 0; i < 16; i++) {
    int e = i * 256 + t; int s = e >> 6, d = e & 63;
    tile[s][d] = src[(size_t)s * 3072 + d];
  }
  __syncthreads();
  unsigned short* dst = Vt + (size_t)bh * 64 * 2048 + stile * 64;
#pragma unroll
  for (int i = 0; i < 16; i++) {
    int e = i * 256 + t; int d = e >> 6, s = e & 63;
    dst[(size_t)d * 2048 + s] = tile[s][d];
  }
}

// ---------- LayerNorm fp32 -> bf16 ----------
__global__ __launch_bounds__(256) void layernorm_bf16(
    const float* __restrict__ x, const float* __restrict__ g,
    const float* __restrict__ be, unsigned short* __restrict__ out) {
  const int row = blockIdx.x;
  const int t = threadIdx.x;
  const float4 v = ((const float4*)(x + (size_t)row * 1024))[t];
  float s = v.x + v.y + v.z + v.w;
  float s2 = v.x * v.x + v.y * v.y + v.z * v.z + v.w * v.w;
#pragma unroll
  for (int d = 32; d > 0; d >>= 1) {
    s += __shfl_down(s, d);
    s2 += __shfl_down(s2, d);
  }
  __shared__ float ps[4], ps2[4], st[2];
  const int lane = t & 63, wave = t >> 6;
  if (lane == 0) { ps[wave] = s; ps2[wave] = s2; }
  __syncthreads();
  if (t == 0) {
    float S = ps[0] + ps[1] + ps[2] + ps[3];
    float S2 = ps2[0] + ps2[1] + ps2[2] + ps2[3];
    float mu = S * (1.0f / 1024.0f);
    float var = S2 * (1.0f / 1024.0f) - mu * mu;
    st[0] = mu; st[1] = rsqrtf(var + 1e-5f);
  }
  __syncthreads();
  float mu = st[0], inv = st[1];
  float4 gv = ((const float4*)g)[t];
  float4 bv = ((const float4*)be)[t];
  ushort4 ov;
  ov.x = f2bf((v.x - mu) * inv * gv.x + bv.x);
  ov.y = f2bf((v.y - mu) * inv * gv.y + bv.y);
  ov.z = f2bf((v.z - mu) * inv * gv.z + bv.z);
  ov.w = f2bf((v.w - mu) * inv * gv.w + bv.w);
  ((ushort4*)(out + (size_t)row * 1024))[t] = ov;
}

// exp2-based tanh-gelu: x / (1 + 2^-(c3*x + c4*x^3))
DEVI float gelu_f(float x) {
  float a = x * (2.3022082f + 0.1029432f * x * x);
  return x / (1.0f + EXP2(-a));
}

// ---------- 8-wave 128x128 GEMM (QKV / FFN1): C = A * B^T ----------------
// Round 17: same verified 2-phase dbuf + row-pair XOR-swizzled LDS as
// gemm_bt, but 512 threads (8 waves, 2M x 4N; per-wave 64x32 output,
// MF=4/NF=2, acc=32 VGPR). Doubles resident waves/CU for the latency-bound
// regime (r16's verified lever). Staging: one gll16 per matrix per thread
// (512 x 16B = 8KB = full 128x32 tile; srow2 bijects rows 0..127, same
// row-pair layout). Read formulas algebraically identical -> same
// measured-0-conflict bank pattern.
// EPI 0: outB = bf16(C);  EPI 2: outB = bf16(gelu(C + bias)).
template <int EPI>
__global__ __launch_bounds__(512, 4) void gemm_bt8(
    const unsigned short* __restrict__ A, const unsigned short* __restrict__ B,
    int M, int N, int K, unsigned short* __restrict__ outB,
    const float* __restrict__ bias) {
  __shared__ __align__(16) unsigned short As[2][128 * 32];
  __shared__ __align__(16) unsigned short Bs[2][128 * 32];
  const int t = threadIdx.x;
  const int lane = t & 63, wave = t >> 6;  // 0..7
  const int wm = wave >> 2, wn = wave & 3;
  const int l15 = lane & 15, lg = lane >> 4;
  const int sl = (t & 7) ^ ((t >> 3) & 7);
  const int srow2 = ((t >> 3) << 1) + (sl >> 2);  // 0..127 (bijective)
  const int scol2 = (sl & 3) * 8;
  // XCD-aware bijective swizzle (nwg % 8 == 0: 768 and 1024)
  const int gx = gridDim.x;
  const int nwg = gx * gridDim.y;
  const int orig = blockIdx.y * gx + blockIdx.x;
  const int swz = (orig & 7) * (nwg >> 3) + (orig >> 3);
  const int bx = swz % gx, by = swz / gx;
  const size_t aBase = (size_t)by * 128 * K;
  const size_t bBase = (size_t)bx * 128 * K;
  f32x4 acc[4][2] = {};

  auto stage = [&](int buf, int kt) {
    gll16(A + aBase + (size_t)srow2 * K + kt + scol2, (char*)&As[buf][0] + t * 16);
    gll16(B + bBase + (size_t)srow2 * K + kt + scol2, (char*)&Bs[buf][0] + t * 16);
  };

  stage(0, 0);
  __syncthreads();
  const int nk = K >> 5;
  for (int ki = 0; ki < nk; ki++) {
    const int cur = ki & 1;
    if (ki + 1 < nk) stage(cur ^ 1, (ki + 1) << 5);  // overlap with compute
    bf16x8 af[4], bfv[2];
#pragma unroll
    for (int m = 0; m < 4; m++) {
      const int R = wm * 64 + m * 16 + l15;
      const int r = R >> 1;
      const int ps = (((R & 1) << 2) | lg) ^ (r & 7);
      af[m] = *(const bf16x8*)&As[cur][r * 64 + ps * 8];
    }
#pragma unroll
    for (int n = 0; n < 2; n++) {
      const int R = wn * 32 + n * 16 + l15;
      const int r = R >> 1;
      const int ps = (((R & 1) << 2) | lg) ^ (r & 7);
      bfv[n] = *(const bf16x8*)&Bs[cur][r * 64 + ps * 8];
    }
#pragma unroll
    for (int m = 0; m < 4; m++)
#pragma unroll
      for (int n = 0; n < 2; n++)
        acc[m][n] = __builtin_amdgcn_mfma_f32_16x16x32_bf16(af[m], bfv[n], acc[m][n], 0, 0, 0);
    __syncthreads();  // drains prefetch + protects cur
  }
  const int rowB = by * 128 + wm * 64;
  const int colB = bx * 128 + wn * 32;
#pragma unroll
  for (int m = 0; m < 4; m++) {
#pragma unroll
    for (int n = 0; n < 2; n++) {
      const int gn = colB + n * 16 + l15;
      float bb = (EPI == 2) ? bias[gn] : 0.0f;
#pragma unroll
      for (int r = 0; r < 4; r++) {
        const int gm = rowB + m * 16 + lg * 4 + r;
        const size_t idx = (size_t)gm * N + gn;
        if (EPI == 0) outB[idx] = f2bf(acc[m][n][r]);
        else          outB[idx] = f2bf(gelu_f(acc[m][n][r] + bb));
      }
    }
  }
}

// ---------- GEMM: 64x128 2-phase dbuf (verified r6/r7): Wo / FFN2 ----------
// EPI 1: outF = res + C ;  EPI 3: outF = res + C + bias
template <int EPI, int TM, int TN>
__global__ __launch_bounds__(256, 4) void gemm_bt(
    const unsigned short* __restrict__ A, const unsigned short* __restrict__ B,
    int M, int N, int K, float* __restrict__ outF,
    const float* __restrict__ res, const float* __restrict__ bias) {
  __shared__ __align__(16) unsigned short As[2][TM * 32];
  __shared__ __align__(16) unsigned short Bs[2][TN * 32];
  constexpr int MF = TM / 32;
  constexpr int NF = TN / 32;
  const int t = threadIdx.x;
  const int lane = t & 63, wave = t >> 6;
  const int wr = wave >> 1, wc = wave & 1;
  const int l15 = lane & 15, lg = lane >> 4;
  const int sl = (t & 7) ^ ((t >> 3) & 7);
  const int srow2 = ((t >> 3) << 1) + (sl >> 2);
  const int scol2 = (sl & 3) * 8;
  const int gx = gridDim.x;
  const int nwg = gx * gridDim.y;
  const int orig = blockIdx.y * gx + blockIdx.x;
  const int swz = (orig & 7) * (nwg >> 3) + (orig >> 3);
  const int bx = swz % gx, by = swz / gx;
  const size_t aBase = (size_t)by * TM * K;
  const size_t bBase = (size_t)bx * TN * K;
  f32x4 acc[MF][NF] = {};

  auto stage = [&](int buf, int kt) {
#pragma unroll
    for (int i = 0; i < TM / 64; i++)
      gll16(A + aBase + (size_t)(srow2 + i * 64) * K + kt + scol2,
            (char*)&As[buf][0] + i * 4096 + t * 16);
#pragma unroll
    for (int i = 0; i < TN / 64; i++)
      gll16(B + bBase + (size_t)(srow2 + i * 64) * K + kt + scol2,
            (char*)&Bs[buf][0] + i * 4096 + t * 16);
  };

  stage(0, 0);
  __syncthreads();
  const int nk = K >> 5;
  for (int ki = 0; ki < nk; ki++) {
    const int cur = ki & 1;
    if (ki + 1 < nk) stage(cur ^ 1, (ki + 1) << 5);
    bf16x8 af[MF], bfv[NF];
#pragma unroll
    for (int m = 0; m < MF; m++) {
      const int R = wr * (TM / 2) + m * 16 + l15;
      const int r = R >> 1;
      const int ps = (((R & 1) << 2) | lg) ^ (r & 7);
      af[m] = *(const bf16x8*)&As[cur][r * 64 + ps * 8];
    }
#pragma unroll
    for (int n = 0; n < NF; n++) {
      const int R = wc * (TN / 2) + n * 16 + l15;
      const int r = R >> 1;
      const int ps = (((R & 1) << 2) | lg) ^ (r & 7);
      bfv[n] = *(const bf16x8*)&Bs[cur][r * 64 + ps * 8];
    }
#pragma unroll
    for (int m = 0; m < MF; m++)
#pragma unroll
      for (int n = 0; n < NF; n++)
        acc[m][n] = __builtin_amdgcn_mfma_f32_16x16x32_bf16(af[m], bfv[n], acc[m][n], 0, 0, 0);
    __syncthreads();
  }
  const int rowB = by * TM + wr * (TM / 2);
  const int colB = bx * TN + wc * (TN / 2);
#pragma unroll
  for (int m = 0; m < MF; m++) {
#pragma unroll
    for (int n = 0; n < NF; n++) {
#pragma unroll
      for (int r = 0; r < 4; r++) {
        int gm = rowB + m * 16 + lg * 4 + r;
        int gn = colB + n * 16 + l15;
        float c = acc[m][n][r];
        size_t idx = (size_t)gm * N + gn;
        if (EPI == 1) outF[idx] = res[idx] + c;
        else          outF[idx] = res[idx] + c + bias[gn];
      }
    }
  }
}

// ---------- flash attention, static-max softmax, QBLK=128, 8 waves --------
// Verified r16: 512-thread blocks, 8 waves x 16 q-rows; occupancy 36.6%,
// 65.9us, 0 conflicts. Unchanged.
__global__ __launch_bounds__(512) void attn_flash(
    const unsigned short* __restrict__ QKV, const unsigned short* __restrict__ Vt,
    unsigned short* __restrict__ attnO) {
  __shared__ __align__(16) unsigned short Ks[2][64 * 64];
  __shared__ __align__(16) unsigned short Vs[2][64 * 64];
  __shared__ __align__(16) unsigned short Ps[128 * 64];
  const int t = threadIdx.x;
  const int lane = t & 63, wave = t >> 6;  // wave 0..7
  const int l15 = lane & 15, lg = lane >> 4;
  const int bid = blockIdx.x;
  const int swzb = (bid & 7) * 64 + (bid >> 3);
  const int qt = swzb & 15;
  const int bh = swzb >> 4;
  const int b = bh >> 4, h = bh & 15;
  const size_t qkvBase = (size_t)b * 2048 * 3072 + (size_t)h * 64;

  bf16x8 aq[2];
  {
    int qrow = qt * 128 + wave * 16 + l15;
    const unsigned short* qp = QKV + qkvBase + (size_t)qrow * 3072;
#pragma unroll
    for (int kc = 0; kc < 2; kc++) {
      aq[kc] = *(const bf16x8*)(qp + kc * 32 + lg * 8);
#pragma unroll
      for (int j = 0; j < 8; j++)
        aq[kc][j] = (__bf16)((float)aq[kc][j] * 0.125f);
    }
  }
  bf16x8 onesf;
#pragma unroll
  for (int j = 0; j < 8; j++) onesf[j] = (__bf16)1.0f;

  const unsigned short* Kg = QKV + qkvBase + 1024;
  const unsigned short* Vg = Vt + (size_t)bh * 64 * 2048;

  f32x4 o[4] = {};
  f32x4 ol = {};
  const float M2 = 4.0f * LOG2E;

  const int srow = t >> 3;                       // 0..63 (512 threads)
  const int scb = (t & 7) * 16;
  const int e = (scb ^ ((srow & 7) << 4)) >> 1;  // pre-swizzled source elem

  auto stage = [&](int buf, int kt) {
    gll16(Kg + (size_t)(kt * 64 + srow) * 3072 + e, (char*)&Ks[buf][0] + t * 16);
    gll16(Vg + (size_t)srow * 2048 + kt * 64 + e, (char*)&Vs[buf][0] + t * 16);
  };

  stage(0, 0);
  __syncthreads();

  for (int kt = 0; kt < 32; kt++) {
    const int cur = kt & 1;
    if (kt < 31) stage(cur ^ 1, kt + 1);

    f32x4 s[4] = {};
#pragma unroll
    for (int n = 0; n < 4; n++) {
#pragma unroll
      for (int kc = 0; kc < 2; kc++) {
        int r = n * 16 + l15;
        int cb = (kc * 64 + lg * 16) ^ ((r & 7) << 4);
        bf16x8 bk = *(const bf16x8*)&Ks[cur][r * 64 + (cb >> 1)];
        s[n] = __builtin_amdgcn_mfma_f32_16x16x32_bf16(aq[kc], bk, s[n], 0, 0, 0);
      }
    }

    const int q0 = wave * 16 + lg * 4;
#pragma unroll
    for (int n = 0; n < 4; n++)
#pragma unroll
      for (int r = 0; r < 4; r++) {
        int q = q0 + r;
        int cb = ((n * 16 + l15) * 2) ^ ((q & 7) << 4);
        float p = EXP2(__builtin_fmaf(s[n][r], LOG2E, -M2));
        Ps[q * 64 + (cb >> 1)] = f2bf_fast(p);
      }

#pragma unroll
    for (int kc = 0; kc < 2; kc++) {
      int qr = wave * 16 + l15;
      int cbp = (kc * 64 + lg * 16) ^ ((qr & 7) << 4);
      bf16x8 pa = *(const bf16x8*)&Ps[qr * 64 + (cbp >> 1)];
      ol = __builtin_amdgcn_mfma_f32_16x16x32_bf16(pa, onesf, ol, 0, 0, 0);
#pragma unroll
      for (int n = 0; n < 4; n++) {
        int dr = n * 16 + l15;
        int cbv = (kc * 64 + lg * 16) ^ ((dr & 7) << 4);
        bf16x8 bv = *(const bf16x8*)&Vs[cur][dr * 64 + (cbv >> 1)];
        o[n] = __builtin_amdgcn_mfma_f32_16x16x32_bf16(pa, bv, o[n], 0, 0, 0);
      }
    }
    __syncthreads();
  }

  const int qrow0 = qt * 128 + wave * 16;
  unsigned short* op = attnO + ((size_t)(b * 2048 + qrow0)) * 1024 + h * 64;
  float inv[4];
#pragma unroll
  for (int r = 0; r < 4; r++) inv[r] = 1.0f / ol[r];
#pragma unroll
  for (int n = 0; n < 4; n++)
#pragma unroll
    for (int r = 0; r < 4; r++) {
      int q = lg * 4 + r;
      op[(size_t)q * 1024 + n * 16 + l15] = f2bf(o[n][r] * inv[r]);
    }
}

// ---------- launch ----------
extern "C" void kernel_launch(void* const* d_in, const int* in_sizes, int n_in,
                              void* d_out, int out_size, void* d_ws, size_t ws_size,
                              hipStream_t stream) {
  const float* x = (const float*)d_in[0];
  const float* Wq = (const float*)d_in[1];
  const float* Wk = (const float*)d_in[2];
  const float* Wv = (const float*)d_in[3];
  const float* Wo = (const float*)d_in[4];
  const float* ln1g = (const float*)d_in[5];
  const float* ln1b = (const float*)d_in[6];
  const float* ln2g = (const float*)d_in[7];
  const float* ln2b = (const float*)d_in[8];
  const float* W1 = (const float*)d_in[9];
  const float* b1 = (const float*)d_in[10];
  const float* W2 = (const float*)d_in[11];
  const float* b2 = (const float*)d_in[12];
  float* out = (float*)d_out;

  char* ws = (char*)d_ws;
  size_t off = 0;
  auto alloc = [&](size_t bytes) {
    void* p = ws + off;
    off += (bytes + 255) & ~(size_t)255;
    return p;
  };
  unsigned short* WB = (unsigned short*)alloc(3072ull * 1024 * 2);   // packed Wq|Wk|Wv
  unsigned short* WoB = (unsigned short*)alloc(1024ull * 1024 * 2);
  unsigned short* W1t = (unsigned short*)alloc(4096ull * 1024 * 2);
  unsigned short* W2t = (unsigned short*)alloc(1024ull * 4096 * 2);
  unsigned short* hb = (unsigned short*)alloc(4096ull * 1024 * 2);   // ln1 out, reused ln2 out
  unsigned short* QKV = (unsigned short*)alloc(4096ull * 3072 * 2);  // reused (with attnb) as ffnb
  unsigned short* attnb = (unsigned short*)alloc(4096ull * 1024 * 2);
  unsigned short* Vtb = (unsigned short*)alloc(32ull * 64 * 2048 * 2);
  float* x2 = (float*)alloc(4096ull * 1024 * 4);
  unsigned short* ffnb = QKV;  // 4096*4096*2 == QKV + attnb (contiguous)
  unsigned short* h2b = hb;

  cvt_weights<<<4096, 256, 0, stream>>>(Wq, Wk, Wv, Wo, WB, WoB);
  transpose_f32_bf16<<<dim3(128, 32), 256, 0, stream>>>(W1, W1t, 1024, 4096);
  transpose_f32_bf16<<<dim3(32, 128), 256, 0, stream>>>(W2, W2t, 4096, 1024);
  layernorm_bf16<<<4096, 256, 0, stream>>>(x, ln1g, ln1b, hb);
  gemm_bt8<0><<<dim3(24, 32), 512, 0, stream>>>(hb, WB, 4096, 3072, 1024,
                                                QKV, nullptr);
  vtrans<<<dim3(32, 32), 256, 0, stream>>>(QKV, Vtb);
  attn_flash<<<512, 512, 0, stream>>>(QKV, Vtb, attnb);
  gemm_bt<1, 64, 128><<<dim3(8, 64), 256, 0, stream>>>(attnb, WoB, 4096, 1024, 1024,
                                                       x2, x, nullptr);
  layernorm_bf16<<<4096, 256, 0, stream>>>(x2, ln2g, ln2b, h2b);
  gemm_bt8<2><<<dim3(32, 32), 512, 0, stream>>>(h2b, W1t, 4096, 4096, 1024,
                                                ffnb, b1);
  gemm_bt<3, 64, 128><<<dim3(8, 64), 256, 0, stream>>>(ffnb, W2t, 4096, 1024, 4096,
                                                       out, x2, b2);
}